// Round 2
// baseline (77.265 us; speedup 1.0000x reference)
//
#include <hip/hip_runtime.h>

#define B_ 2
#define N_ 8192
#define K_ 16
#define C_ 64
#define PE_ 32
#define HID_ 16

// ---------------- Kernel 1: ht[b][n][c] = relu(sum_c' W1[c][c'] * f[b][c'][n] + b1[c])
// Block = 256 threads, handles 64 consecutive flattened (b*N+n) points.
__global__ __launch_bounds__(256) void k1_conv(
    const float* __restrict__ f, const float* __restrict__ W1,
    const float* __restrict__ b1, float* __restrict__ ht) {
  __shared__ float sf[C_ * 64];  // [c][nl]
  const int t = threadIdx.x;
  const int g0 = blockIdx.x * 64;          // flattened b*N + n base
  const int b = g0 >> 13;                  // / N_
  const int n0 = g0 & (N_ - 1);
  // stage f tile: 64 channels x 64 points, coalesced
  for (int idx = t; idx < C_ * 64; idx += 256) {
    int c = idx >> 6, nl = idx & 63;
    sf[c * 64 + nl] = f[(size_t)(b * C_ + c) * N_ + n0 + nl];
  }
  __syncthreads();
  const int nl = t & 63;
  const int q = t >> 6;  // output quarter: oc in [q*16, q*16+16)
  float fv[C_];
  #pragma unroll
  for (int c = 0; c < C_; ++c) fv[c] = sf[c * 64 + nl];
  float* op = ht + (size_t)(g0 + nl) * C_ + q * 16;
  #pragma unroll
  for (int o4 = 0; o4 < 4; ++o4) {
    float r[4];
    #pragma unroll
    for (int u = 0; u < 4; ++u) {
      const int oc = q * 16 + o4 * 4 + u;
      float acc = b1[oc];                  // uniform -> s_load
      #pragma unroll
      for (int c = 0; c < C_; ++c) acc = fmaf(W1[oc * C_ + c], fv[c], acc);
      r[u] = fmaxf(acc, 0.f);
    }
    reinterpret_cast<float4*>(op)[o4] = make_float4(r[0], r[1], r[2], r[3]);
  }
}

// ---------------- Kernel 2: fout[b][c][n] = max_k( pe[b][c][n][k] + ht[b][knn[b][n][k]][c] )
// Block = 256 threads (4 waves), handles TN=32 consecutive n. Wave = one n at a time, lane = c.
#define TN 32
__global__ __launch_bounds__(256) void k2_agg(
    const float* __restrict__ pe, const float* __restrict__ ht,
    const int* __restrict__ knn, float* __restrict__ fout) {
  __shared__ float tile[C_ * (TN + 1)];
  const int g0 = blockIdx.x * TN;          // flattened b*N + n base
  const int b = g0 >> 13;
  const int n0 = g0 & (N_ - 1);
  const int lane = threadIdx.x & 63;       // channel
  const int w = threadIdx.x >> 6;          // wave id 0..3
  #pragma unroll
  for (int j = 0; j < TN / 4; ++j) {
    const int nl = w * (TN / 4) + j;
    const int n = n0 + nl;
    const int* kn = knn + (size_t)(b * N_ + n) * K_;           // uniform
    const float4* pe4 =
        reinterpret_cast<const float4*>(pe + ((size_t)(b * C_ + lane) * N_ + n) * K_);
    float4 q0 = pe4[0], q1 = pe4[1], q2 = pe4[2], q3 = pe4[3];
    float pv[16] = {q0.x, q0.y, q0.z, q0.w, q1.x, q1.y, q1.z, q1.w,
                    q2.x, q2.y, q2.z, q2.w, q3.x, q3.y, q3.z, q3.w};
    float acc = -3.402823466e+38f;
    #pragma unroll
    for (int k = 0; k < K_; ++k) {
      const int id = kn[k];
      const float hv = ht[(size_t)(b * N_ + id) * C_ + lane];  // coalesced 256B, L2-hit
      acc = fmaxf(acc, pv[k] + hv);
    }
    tile[lane * (TN + 1) + nl] = acc;
  }
  __syncthreads();
  const int nl2 = threadIdx.x & 31;
  const int c0 = threadIdx.x >> 5;  // 0..7
  #pragma unroll
  for (int r = 0; r < 8; ++r) {
    const int c = c0 + r * 8;
    fout[(size_t)(b * C_ + c) * N_ + n0 + nl2] = tile[c * (TN + 1) + nl2];
  }
}

// ---------------- Kernel 3: KDE offset generator. Block = 256 threads = 16 groups.
__global__ __launch_bounds__(256) void k3_kde(
    const float* __restrict__ p, const int* __restrict__ knn,
    const float* __restrict__ Wpe, const float* __restrict__ bpe,
    const float* __restrict__ Wh1, const float* __restrict__ bh1,
    const float* __restrict__ Wh2, const float* __restrict__ bh2,
    float* __restrict__ delta) {
  __shared__ float sWpe[PE_ * 3], sbpe[PE_];
  __shared__ float sWh1[HID_ * PE_], sbh1[HID_];
  __shared__ float sWh2[3 * HID_], sbh2[3];
  __shared__ float sc[16 * K_ * 3];  // [g][i][d]
  const int t = threadIdx.x;
  for (int i = t; i < PE_ * 3; i += 256) sWpe[i] = Wpe[i];
  for (int i = t; i < PE_; i += 256) sbpe[i] = bpe[i];
  for (int i = t; i < HID_ * PE_; i += 256) sWh1[i] = Wh1[i];
  for (int i = t; i < HID_; i += 256) sbh1[i] = bh1[i];
  for (int i = t; i < 3 * HID_; i += 256) sWh2[i] = Wh2[i];
  for (int i = t; i < 3; i += 256) sbh2[i] = bh2[i];
  const int g = t >> 4, i = t & 15;
  const int gid = blockIdx.x * 16 + g;   // flattened b*N + n
  const int b = gid >> 13;
  const int idx = knn[(size_t)gid * K_ + i];
  const float* pp = p + (size_t)(b * N_ + idx) * 3;
  sc[g * 48 + i * 3 + 0] = pp[0];
  sc[g * 48 + i * 3 + 1] = pp[1];
  sc[g * 48 + i * 3 + 2] = pp[2];
  __syncthreads();

  const float INV2S = 0.49999975f;   // 1/(2*sigma^2 + eps)
  const float COEF = 0.39894225f;    // 1/sqrt(2*pi*sigma^2 + eps)
  const float ci0 = sc[g * 48 + i * 3 + 0];
  const float ci1 = sc[g * 48 + i * 3 + 1];
  const float ci2 = sc[g * 48 + i * 3 + 2];
  float pek[PE_];
  #pragma unroll
  for (int d = 0; d < PE_; ++d) pek[d] = 0.f;
  float kacc = 0.f;
  #pragma unroll 4
  for (int j = 0; j < K_; ++j) {
    const float dx = ci0 - sc[g * 48 + j * 3 + 0];
    const float dy = ci1 - sc[g * 48 + j * 3 + 1];
    const float dz = ci2 - sc[g * 48 + j * 3 + 2];
    const float d2 = dx * dx + dy * dy + dz * dz;
    kacc += __expf(-d2 * INV2S);
    #pragma unroll
    for (int d = 0; d < PE_; ++d) {
      const float v = fmaf(sWpe[d * 3 + 0], dx,
                      fmaf(sWpe[d * 3 + 1], dy,
                      fmaf(sWpe[d * 3 + 2], dz, sbpe[d])));
      pek[d] += fmaxf(v, 0.f);
    }
  }
  float kde = COEF * kacc;
  float m = kde;
  m = fmaxf(m, __shfl_xor(m, 1));
  m = fmaxf(m, __shfl_xor(m, 2));
  m = fmaxf(m, __shfl_xor(m, 4));
  m = fmaxf(m, __shfl_xor(m, 8));
  const float s = (kde / (m + 1e-6f)) * (1.f / 16.f);  // kdn * mean-scale
  #pragma unroll
  for (int d = 0; d < PE_; ++d) pek[d] *= s;
  float o0 = sbh2[0], o1 = sbh2[1], o2 = sbh2[2];
  #pragma unroll
  for (int h = 0; h < HID_; ++h) {
    float a = sbh1[h];
    #pragma unroll
    for (int d = 0; d < PE_; ++d) a = fmaf(sWh1[h * PE_ + d], pek[d], a);
    a = fmaxf(a, 0.f);
    o0 = fmaf(sWh2[0 * HID_ + h], a, o0);
    o1 = fmaf(sWh2[1 * HID_ + h], a, o1);
    o2 = fmaf(sWh2[2 * HID_ + h], a, o2);
  }
  float* dp = delta + ((size_t)gid * K_ + i) * 3;
  dp[0] = o0;
  dp[1] = o1;
  dp[2] = o2;
}

extern "C" void kernel_launch(void* const* d_in, const int* in_sizes, int n_in,
                              void* d_out, int out_size, void* d_ws, size_t ws_size,
                              hipStream_t stream) {
  // setup_inputs() dict order: p, f, pe, W1, b1, Wpe, bpe, Wh1, bh1, Wh2, bh2, knn_idx
  const float* p   = (const float*)d_in[0];
  const float* f   = (const float*)d_in[1];
  const float* pe  = (const float*)d_in[2];
  const float* W1  = (const float*)d_in[3];
  const float* b1  = (const float*)d_in[4];
  const float* Wpe = (const float*)d_in[5];
  const float* bpe = (const float*)d_in[6];
  const float* Wh1 = (const float*)d_in[7];
  const float* bh1 = (const float*)d_in[8];
  const float* Wh2 = (const float*)d_in[9];
  const float* bh2 = (const float*)d_in[10];
  const int* knn   = (const int*)d_in[11];
  float* fout  = (float*)d_out;                        // [B,C,N]
  float* delta = (float*)d_out + (size_t)B_ * C_ * N_; // [B*N,K,3]
  float* ht = (float*)d_ws;                            // [B,N,C] = 4 MB scratch

  k1_conv<<<(B_ * N_) / 64, 256, 0, stream>>>(f, W1, b1, ht);
  k2_agg<<<(B_ * N_) / TN, 256, 0, stream>>>(pe, ht, knn, fout);
  k3_kde<<<(B_ * N_) / 16, 256, 0, stream>>>(p, knn, Wpe, bpe, Wh1, bh1, Wh2, bh2, delta);
}